// Round 1
// baseline (4381.257 us; speedup 1.0000x reference)
//
#include <hip/hip_runtime.h>

#define N_NODES 100000
#define N_EDGES 1600000

// ---------------- scatter layer 1: agg64[dst] += x[src], deg[dst] += 1 ----------------
// 16 threads per edge, float4 per thread (64 floats/row).
__global__ __launch_bounds__(256) void k_scatter1(
    const float* __restrict__ x, const int* __restrict__ src, const int* __restrict__ dst,
    float* __restrict__ agg, float* __restrict__ deg)
{
    int t = blockIdx.x * 256 + threadIdx.x;      // E*16 = 25,600,000 = 100000*256 exact
    int e = t >> 4, sub = t & 15;
    int s = src[e], d = dst[e];
    float4 v = *reinterpret_cast<const float4*>(x + (size_t)s * 64 + sub * 4);
    float* o = agg + (size_t)d * 64 + sub * 4;
    atomicAdd(o + 0, v.x); atomicAdd(o + 1, v.y);
    atomicAdd(o + 2, v.z); atomicAdd(o + 3, v.w);
    if (sub == 0) atomicAdd(deg + d, 1.0f);
}

// ---------------- scatter layer 2: agg128[dst] += h1[src] ----------------
// 32 threads per edge, float4 per thread (128 floats/row).
__global__ __launch_bounds__(256) void k_scatter2(
    const float* __restrict__ h1, const int* __restrict__ src, const int* __restrict__ dst,
    float* __restrict__ agg)
{
    int t = blockIdx.x * 256 + threadIdx.x;      // E*32 = 51,200,000 = 200000*256 exact
    int e = t >> 5, sub = t & 31;
    int s = src[e], d = dst[e];
    float4 v = *reinterpret_cast<const float4*>(h1 + (size_t)s * 128 + sub * 4);
    float* o = agg + (size_t)d * 128 + sub * 4;
    atomicAdd(o + 0, v.x); atomicAdd(o + 1, v.y);
    atomicAdd(o + 2, v.z); atomicAdd(o + 3, v.w);
}

// ---------------- dense layer 1: h1 = relu(mean_agg @ Wl1 + x @ Wr1 + b1) ----------------
// 32 nodes per block. Node rows staged row-major in LDS (padded, broadcast scalar reads).
// Weight rows streamed as float4 from global (L1-resident, identical rows for every block).
__global__ __launch_bounds__(256) void k_dense1(
    const float* __restrict__ x, const float* __restrict__ agg, const float* __restrict__ deg,
    const float* __restrict__ Wl, const float* __restrict__ Wr, const float* __restrict__ b,
    float* __restrict__ h1)
{
    __shared__ float la[32][68];   // 68: keeps 16B row alignment, breaks bank stride
    __shared__ float lx[32][68];
    const int tile = blockIdx.x * 32;           // 100000 = 3125 * 32 exact
    const int tid = threadIdx.x;

    #pragma unroll
    for (int r = 0; r < 8; ++r) {               // 2048 elements per array
        int flat = r * 256 + tid;
        int node = flat >> 6, k = flat & 63;
        int n = tile + node;
        float rd = 1.0f / fmaxf(deg[n], 1.0f);
        la[node][k] = agg[(size_t)n * 64 + k] * rd;
        lx[node][k] = x[(size_t)n * 64 + k];
    }
    __syncthreads();

    const int jg = tid & 31, ng = tid >> 5;
    const int j4 = jg * 4, nb = ng * 4;
    float acc[4][4] = {};
    for (int k = 0; k < 64; ++k) {
        float4 w1 = *reinterpret_cast<const float4*>(Wl + k * 128 + j4);
        float4 w2 = *reinterpret_cast<const float4*>(Wr + k * 128 + j4);
        #pragma unroll
        for (int i = 0; i < 4; ++i) {
            float a = la[nb + i][k], xx = lx[nb + i][k];
            acc[i][0] += a * w1.x + xx * w2.x;
            acc[i][1] += a * w1.y + xx * w2.y;
            acc[i][2] += a * w1.z + xx * w2.z;
            acc[i][3] += a * w1.w + xx * w2.w;
        }
    }
    float4 bb = *reinterpret_cast<const float4*>(b + j4);
    #pragma unroll
    for (int i = 0; i < 4; ++i) {
        int n = tile + nb + i;
        float4 o;
        o.x = fmaxf(acc[i][0] + bb.x, 0.0f);
        o.y = fmaxf(acc[i][1] + bb.y, 0.0f);
        o.z = fmaxf(acc[i][2] + bb.z, 0.0f);
        o.w = fmaxf(acc[i][3] + bb.w, 0.0f);
        *reinterpret_cast<float4*>(h1 + (size_t)n * 128 + j4) = o;
    }
}

// ---------------- dense layer 2 + heads ----------------
// h2 = relu(mean_agg2 @ Wl2 + h1 @ Wr2 + b2); out1 = h2@Wh+bh; out2 = h2@Wm+bm.
// h2 never leaves the block (stored to LDS, heads computed in-block).
__global__ __launch_bounds__(256) void k_dense2(
    const float* __restrict__ h1, const float* __restrict__ agg, const float* __restrict__ deg,
    const float* __restrict__ Wl, const float* __restrict__ Wr, const float* __restrict__ b,
    const float* __restrict__ Wh, const float* __restrict__ bh,
    const float* __restrict__ Wm, const float* __restrict__ bm,
    float* __restrict__ out1, float* __restrict__ out2)
{
    __shared__ float la[32][132];  // 132: 16B-aligned rows
    __shared__ float lh[32][132];
    const int tile = blockIdx.x * 32;
    const int tid = threadIdx.x;

    #pragma unroll
    for (int r = 0; r < 16; ++r) {              // 4096 elements per array
        int flat = r * 256 + tid;
        int node = flat >> 7, k = flat & 127;
        int n = tile + node;
        float rd = 1.0f / fmaxf(deg[n], 1.0f);
        la[node][k] = agg[(size_t)n * 128 + k] * rd;
        lh[node][k] = h1[(size_t)n * 128 + k];
    }
    __syncthreads();

    const int jg = tid & 31, ng = tid >> 5;
    const int j4 = jg * 4, nb = ng * 4;
    float acc[4][4] = {};
    for (int k = 0; k < 128; ++k) {
        float4 w1 = *reinterpret_cast<const float4*>(Wl + k * 128 + j4);
        float4 w2 = *reinterpret_cast<const float4*>(Wr + k * 128 + j4);
        #pragma unroll
        for (int i = 0; i < 4; ++i) {
            float a = la[nb + i][k], hh = lh[nb + i][k];
            acc[i][0] += a * w1.x + hh * w2.x;
            acc[i][1] += a * w1.y + hh * w2.y;
            acc[i][2] += a * w1.z + hh * w2.z;
            acc[i][3] += a * w1.w + hh * w2.w;
        }
    }
    __syncthreads();   // everyone done reading la/lh before h2 overwrites la

    float4 bb = *reinterpret_cast<const float4*>(b + j4);
    #pragma unroll
    for (int i = 0; i < 4; ++i) {
        float4 o;
        o.x = fmaxf(acc[i][0] + bb.x, 0.0f);
        o.y = fmaxf(acc[i][1] + bb.y, 0.0f);
        o.z = fmaxf(acc[i][2] + bb.z, 0.0f);
        o.w = fmaxf(acc[i][3] + bb.w, 0.0f);
        *reinterpret_cast<float4*>(&la[nb + i][j4]) = o;   // h2 tile into LDS
    }
    __syncthreads();

    // heads: 32 nodes x (3 classes + 8 materials) = 352 dot products of length 128
    for (int t = tid; t < 352; t += 256) {
        int node = t / 11, o = t - node * 11;
        const float* h2 = &la[node][0];
        if (o < 3) {
            float s = bh[o];
            for (int k = 0; k < 128; ++k) s += h2[k] * Wh[k * 3 + o];
            out1[(size_t)(tile + node) * 3 + o] = s;
        } else {
            int m = o - 3;
            float s = bm[m];
            for (int k = 0; k < 128; ++k) s += h2[k] * Wm[k * 8 + m];
            out2[(size_t)(tile + node) * 8 + m] = s;
        }
    }
}

extern "C" void kernel_launch(void* const* d_in, const int* in_sizes, int n_in,
                              void* d_out, int out_size, void* d_ws, size_t ws_size,
                              hipStream_t stream) {
    const float* x   = (const float*)d_in[0];
    const int*   ei  = (const int*)d_in[1];
    const int*   src = ei;
    const int*   dst = ei + N_EDGES;
    const float* Wl1 = (const float*)d_in[2];
    const float* Wr1 = (const float*)d_in[3];
    const float* b1  = (const float*)d_in[4];
    const float* Wl2 = (const float*)d_in[5];
    const float* Wr2 = (const float*)d_in[6];
    const float* b2  = (const float*)d_in[7];
    const float* Wh  = (const float*)d_in[8];
    const float* bh  = (const float*)d_in[9];
    const float* Wm  = (const float*)d_in[10];
    const float* bm  = (const float*)d_in[11];

    float* out1 = (float*)d_out;                       // [N,3]
    float* out2 = out1 + (size_t)N_NODES * 3;          // [N,8]

    char* ws  = (char*)d_ws;
    float* deg = (float*)ws;                                           // N floats
    float* h1  = (float*)(ws + 524288);                                // N*128 floats
    float* agg = (float*)(ws + 524288 + (size_t)N_NODES * 128 * 4);    // N*128 floats (layer1 uses N*64)

    // zero accumulators (harness poisons ws with 0xAA and never re-poisons)
    hipMemsetAsync(deg, 0, N_NODES * sizeof(float), stream);
    hipMemsetAsync(agg, 0, (size_t)N_NODES * 64 * sizeof(float), stream);

    k_scatter1<<<100000, 256, 0, stream>>>(x, src, dst, agg, deg);
    k_dense1<<<3125, 256, 0, stream>>>(x, agg, deg, Wl1, Wr1, b1, h1);

    hipMemsetAsync(agg, 0, (size_t)N_NODES * 128 * sizeof(float), stream);
    k_scatter2<<<200000, 256, 0, stream>>>(h1, src, dst, agg);
    k_dense2<<<3125, 256, 0, stream>>>(h1, agg, deg, Wl2, Wr2, b2, Wh, bh, Wm, bm, out1, out2);
}

// Round 2
// 989.289 us; speedup vs baseline: 4.4287x; 4.4287x over previous
//
#include <hip/hip_runtime.h>

#define N_NODES 100000
#define N_EDGES 1600000

// ================= CSR build =================
__global__ __launch_bounds__(256) void k_hist(const int* __restrict__ dst, int* __restrict__ deg) {
    int e = blockIdx.x * 256 + threadIdx.x;
    if (e < N_EDGES) atomicAdd(&deg[dst[e]], 1);
}

// single-block exclusive scan of deg -> rowstart[0..N]
__global__ __launch_bounds__(1024) void k_scan(const int* __restrict__ deg, int* __restrict__ rowstart) {
    __shared__ int wsum[16];
    __shared__ int carry;
    const int tid = threadIdx.x, lane = tid & 63, wid = tid >> 6;
    if (tid == 0) carry = 0;
    __syncthreads();
    for (int base = 0; base < N_NODES; base += 1024) {
        int i = base + tid;
        int v = (i < N_NODES) ? deg[i] : 0;
        int s = v;
        #pragma unroll
        for (int off = 1; off < 64; off <<= 1) {
            int t = __shfl_up(s, off);
            if (lane >= off) s += t;
        }
        if (lane == 63) wsum[wid] = s;
        __syncthreads();
        if (wid == 0 && lane < 16) {
            int w = wsum[lane];
            #pragma unroll
            for (int off = 1; off < 16; off <<= 1) {
                int t = __shfl_up(w, off);
                if (lane >= off) w += t;
            }
            wsum[lane] = w;
        }
        __syncthreads();
        int wexcl = (wid == 0) ? 0 : wsum[wid - 1];
        int c = carry;
        if (i < N_NODES) rowstart[i] = c + wexcl + s - v;
        __syncthreads();
        if (tid == 0) carry = c + wsum[15];
        __syncthreads();
    }
    if (tid == 0) rowstart[N_NODES] = carry;
}

__global__ __launch_bounds__(256) void k_fill(const int* __restrict__ src, const int* __restrict__ dst,
                                             int* __restrict__ cursor, int* __restrict__ srcs_sorted) {
    int e = blockIdx.x * 256 + threadIdx.x;
    if (e < N_EDGES) {
        int d = dst[e];
        int p = atomicAdd(&cursor[d], 1);
        srcs_sorted[p] = src[e];
    }
}

// ================= layer 1 (fused gather-mean + dense + relu) =================
// h1 = relu(mean_{src in N(n)} x[src] @ Wl1 + x[n] @ Wr1 + b1)
// 32 nodes/block, 4 waves; aggregation: one wave per node (1 float/lane), 8 nodes/wave.
__global__ __launch_bounds__(256) void k_layer1(
    const float* __restrict__ x, const int* __restrict__ rowstart, const int* __restrict__ srcs,
    const float* __restrict__ Wl, const float* __restrict__ Wr, const float* __restrict__ b,
    float* __restrict__ h1)
{
    __shared__ float la[32][68];   // mean-aggregated rows (pre-scaled)
    __shared__ float lx[32][68];   // root rows
    const int tile = blockIdx.x * 32;          // 100000 = 3125*32
    const int tid = threadIdx.x, lane = tid & 63, wid = tid >> 6;

    #pragma unroll
    for (int r = 0; r < 8; ++r) {
        int flat = r * 256 + tid;
        int node = flat >> 6, k = flat & 63;
        lx[node][k] = x[(size_t)(tile + node) * 64 + k];
    }

    for (int it = 0; it < 8; ++it) {
        int node = wid * 8 + it;
        int n = tile + node;
        int e0 = rowstart[n], e1 = rowstart[n + 1];
        float acc = 0.0f;
        for (int e = e0; e < e1; ++e) {
            int s = srcs[e];
            acc += x[(size_t)s * 64 + lane];
        }
        float rd = (e1 > e0) ? (1.0f / (float)(e1 - e0)) : 1.0f;
        la[node][lane] = acc * rd;
    }
    __syncthreads();

    const int jg = tid & 31, ng = tid >> 5;
    const int j4 = jg * 4, nb = ng * 4;
    float acc[4][4] = {};
    for (int k = 0; k < 64; ++k) {
        float4 w1 = *reinterpret_cast<const float4*>(Wl + k * 128 + j4);
        float4 w2 = *reinterpret_cast<const float4*>(Wr + k * 128 + j4);
        #pragma unroll
        for (int i = 0; i < 4; ++i) {
            float a = la[nb + i][k], xx = lx[nb + i][k];
            acc[i][0] += a * w1.x + xx * w2.x;
            acc[i][1] += a * w1.y + xx * w2.y;
            acc[i][2] += a * w1.z + xx * w2.z;
            acc[i][3] += a * w1.w + xx * w2.w;
        }
    }
    float4 bb = *reinterpret_cast<const float4*>(b + j4);
    #pragma unroll
    for (int i = 0; i < 4; ++i) {
        int n = tile + nb + i;
        float4 o;
        o.x = fmaxf(acc[i][0] + bb.x, 0.0f);
        o.y = fmaxf(acc[i][1] + bb.y, 0.0f);
        o.z = fmaxf(acc[i][2] + bb.z, 0.0f);
        o.w = fmaxf(acc[i][3] + bb.w, 0.0f);
        *reinterpret_cast<float4*>(h1 + (size_t)n * 128 + j4) = o;
    }
}

// ================= layer 2 + heads (fused gather-mean + dense + relu + 2 heads) =================
__global__ __launch_bounds__(256) void k_layer2(
    const float* __restrict__ h1, const int* __restrict__ rowstart, const int* __restrict__ srcs,
    const float* __restrict__ Wl, const float* __restrict__ Wr, const float* __restrict__ b,
    const float* __restrict__ Wh, const float* __restrict__ bh,
    const float* __restrict__ Wm, const float* __restrict__ bm,
    float* __restrict__ out1, float* __restrict__ out2)
{
    __shared__ float la[32][132];
    __shared__ float lh[32][132];
    const int tile = blockIdx.x * 32;
    const int tid = threadIdx.x, lane = tid & 63, wid = tid >> 6;

    #pragma unroll
    for (int r = 0; r < 16; ++r) {
        int flat = r * 256 + tid;
        int node = flat >> 7, k = flat & 127;
        lh[node][k] = h1[(size_t)(tile + node) * 128 + k];
    }

    for (int it = 0; it < 8; ++it) {
        int node = wid * 8 + it;
        int n = tile + node;
        int e0 = rowstart[n], e1 = rowstart[n + 1];
        float ax = 0.0f, ay = 0.0f;
        for (int e = e0; e < e1; ++e) {
            int s = srcs[e];
            float2 v = *reinterpret_cast<const float2*>(h1 + (size_t)s * 128 + lane * 2);
            ax += v.x; ay += v.y;
        }
        float rd = (e1 > e0) ? (1.0f / (float)(e1 - e0)) : 1.0f;
        float2 o; o.x = ax * rd; o.y = ay * rd;
        *reinterpret_cast<float2*>(&la[node][lane * 2]) = o;
    }
    __syncthreads();

    const int jg = tid & 31, ng = tid >> 5;
    const int j4 = jg * 4, nb = ng * 4;
    float acc[4][4] = {};
    for (int k = 0; k < 128; ++k) {
        float4 w1 = *reinterpret_cast<const float4*>(Wl + k * 128 + j4);
        float4 w2 = *reinterpret_cast<const float4*>(Wr + k * 128 + j4);
        #pragma unroll
        for (int i = 0; i < 4; ++i) {
            float a = la[nb + i][k], hh = lh[nb + i][k];
            acc[i][0] += a * w1.x + hh * w2.x;
            acc[i][1] += a * w1.y + hh * w2.y;
            acc[i][2] += a * w1.z + hh * w2.z;
            acc[i][3] += a * w1.w + hh * w2.w;
        }
    }
    __syncthreads();   // done reading la/lh

    float4 bb = *reinterpret_cast<const float4*>(b + j4);
    #pragma unroll
    for (int i = 0; i < 4; ++i) {
        float4 o;
        o.x = fmaxf(acc[i][0] + bb.x, 0.0f);
        o.y = fmaxf(acc[i][1] + bb.y, 0.0f);
        o.z = fmaxf(acc[i][2] + bb.z, 0.0f);
        o.w = fmaxf(acc[i][3] + bb.w, 0.0f);
        *reinterpret_cast<float4*>(&la[nb + i][j4]) = o;   // h2 tile into LDS
    }
    __syncthreads();

    for (int t = tid; t < 352; t += 256) {
        int node = t / 11, o = t - node * 11;
        const float* h2 = &la[node][0];
        if (o < 3) {
            float s = bh[o];
            for (int k = 0; k < 128; ++k) s += h2[k] * Wh[k * 3 + o];
            out1[(size_t)(tile + node) * 3 + o] = s;
        } else {
            int m = o - 3;
            float s = bm[m];
            for (int k = 0; k < 128; ++k) s += h2[k] * Wm[k * 8 + m];
            out2[(size_t)(tile + node) * 8 + m] = s;
        }
    }
}

extern "C" void kernel_launch(void* const* d_in, const int* in_sizes, int n_in,
                              void* d_out, int out_size, void* d_ws, size_t ws_size,
                              hipStream_t stream) {
    const float* x   = (const float*)d_in[0];
    const int*   ei  = (const int*)d_in[1];
    const int*   src = ei;
    const int*   dst = ei + N_EDGES;
    const float* Wl1 = (const float*)d_in[2];
    const float* Wr1 = (const float*)d_in[3];
    const float* b1  = (const float*)d_in[4];
    const float* Wl2 = (const float*)d_in[5];
    const float* Wr2 = (const float*)d_in[6];
    const float* b2  = (const float*)d_in[7];
    const float* Wh  = (const float*)d_in[8];
    const float* bh  = (const float*)d_in[9];
    const float* Wm  = (const float*)d_in[10];
    const float* bm  = (const float*)d_in[11];

    float* out1 = (float*)d_out;                   // [N,3]
    float* out2 = out1 + (size_t)N_NODES * 3;      // [N,8]

    char* ws = (char*)d_ws;
    int*   deg      = (int*)(ws);                  // 100000 ints
    int*   rowstart = (int*)(ws + (512 << 10));    // 100001 ints
    int*   cursor   = (int*)(ws + (1024 << 10));   // 100000 ints
    int*   srcs     = (int*)(ws + (1536 << 10));   // 1.6M ints (6.4 MB)
    float* h1       = (float*)(ws + (8192 << 10)); // 100000*128 floats (51.2 MB)

    hipMemsetAsync(deg, 0, N_NODES * sizeof(int), stream);
    k_hist<<<6250, 256, 0, stream>>>(dst, deg);
    k_scan<<<1, 1024, 0, stream>>>(deg, rowstart);
    hipMemcpyAsync(cursor, rowstart, N_NODES * sizeof(int), hipMemcpyDeviceToDevice, stream);
    k_fill<<<6250, 256, 0, stream>>>(src, dst, cursor, srcs);

    k_layer1<<<3125, 256, 0, stream>>>(x, rowstart, srcs, Wl1, Wr1, b1, h1);
    k_layer2<<<3125, 256, 0, stream>>>(h1, rowstart, srcs, Wl2, Wr2, b2, Wh, bh, Wm, bm, out1, out2);
}